// Round 1
// baseline (4688.926 us; speedup 1.0000x reference)
//
#include <hip/hip_runtime.h>
#include <hip/hip_bf16.h>

// MatchLSTM boundary-pointer model on MI355X (gfx950).
// B=32 T=400 J=30 V=50000 D=150 H=150 L=2. Output [B,2,401].
//
// Pipeline:
//  1) sniff: runtime-detect whether float inputs are fp32 or bf16 (bit-pattern
//     statistics of E's low 16 bits), flag stored in ws.
//  2) convert_weights: all 29 float weight inputs -> packed fp32 block in ws.
//  3) rowproj (generic row-tiled projection kernel) x8: embedding+Wih
//     projections, Hq@Wq, P=Hq@Wih_q^T (attention folding), Hp@Wp(+gate_bias),
//     Hp@Wih_x(+bih), Hr@ptr_W1.
//  4) gru_scan: 1 block/batch, Whh ROWS HELD IN VGPRS (150/thread) — avoids
//     the 270KB/step per-CU L2 stream that would bound at ~4200 clk/step.
//  5) match_scan: 1 block/(batch,dir); m_Whh rows + Wr column-segments in
//     VGPRs, P (30x450) in LDS; attention softmax per step; writes Hr.
//  6) ptr_scan: 2 pointer steps, block-wide softmax over 401, writes output
//     in fp32 or bf16 per the sniffed flag.

namespace {

constexpr int NBATCH = 32;
constexpr int TLEN   = 400;
constexpr int JQ     = 30;
constexpr int HID    = 150;
constexpr int T1     = 401;

__device__ __forceinline__ float sigm(float x){ return 1.f/(1.f+__expf(-x)); }
__device__ __forceinline__ float tanh_f(float x){
  float e = __expf(-2.f*fabsf(x));
  float t = (1.f-e)/(1.f+e);
  return x < 0.f ? -t : t;
}
__device__ __forceinline__ float bf2f(unsigned short u){
  union { unsigned int i; float f; } c; c.i = ((unsigned int)u)<<16; return c.f;
}

#define NW 29
struct WDesc { const void* src[NW]; int off[NW+1]; };

// ---- dtype sniff: bf16-packed-as-words have concentrated exponent bits in
// bits[14:8]; fp32 random mantissa bits are ~uniform there.
__global__ void sniff_kernel(const unsigned int* __restrict__ bits, int* __restrict__ flag){
  __shared__ int cnt;
  if (threadIdx.x==0) cnt = 0;
  __syncthreads();
  int hit = 0;
  #pragma unroll
  for (int i=0;i<4;i++){
    unsigned int w = bits[threadIdx.x*4+i];
    unsigned int b = (w>>8)&0x7Fu;
    if (b==0u || (b>=0x38u && b<=0x3Fu)) hit++;
  }
  atomicAdd(&cnt, hit);
  __syncthreads();
  if (threadIdx.x==0) *flag = (cnt > 768) ? 1 : 0;   // bf16: ~1024 hits, fp32: ~72
}

__global__ void convert_weights_kernel(WDesc d, float* __restrict__ out, const int* __restrict__ flag){
  const int isbf = *flag;
  const int total = d.off[NW];
  for (int e = blockIdx.x*blockDim.x+threadIdx.x; e < total; e += gridDim.x*blockDim.x){
    int j = 0;
    while (e >= d.off[j+1]) j++;
    int i = e - d.off[j];
    out[e] = isbf ? bf2f(((const unsigned short*)d.src[j])[i])
                  : ((const float*)d.src[j])[i];
  }
}

// ---- generic row-tiled projection: out[row,k] = bias[k] + sum_i x[row,i]*W(i,k)
// mode 0: W[i*ldw + k]   (k-contiguous, coalesced)
// mode 1: W[k*ldw + offw + i]  (per-thread row stream)
// optional gather: row r of X is Etab[gather[r]*inner + i] (fp32 or bf16 per flag)
__global__ __launch_bounds__(512) void rowproj_kernel(
    const float* __restrict__ Xrows,
    const int* __restrict__ gather, const void* __restrict__ Etab, const int* __restrict__ bfflag,
    const float* __restrict__ W, const float* __restrict__ bias,
    float* __restrict__ out, int rows, int K, int inner, int mode, int ldw, int offw)
{
  __shared__ float xs[8][304];
  const int r0 = blockIdx.x*8;
  int nr = rows - r0; if (nr > 8) nr = 8;
  if (nr <= 0) return;
  const int isbf = gather ? *bfflag : 0;
  for (int e = threadIdx.x; e < nr*inner; e += blockDim.x){
    int r = e/inner, i = e - r*inner;
    float v;
    if (gather){
      size_t base = (size_t)gather[r0+r]*inner + i;
      v = isbf ? bf2f(((const unsigned short*)Etab)[base]) : ((const float*)Etab)[base];
    } else {
      v = Xrows[(size_t)(r0+r)*inner + i];
    }
    xs[r][i] = v;
  }
  __syncthreads();
  for (int k = threadIdx.x; k < K; k += blockDim.x){
    float b0 = bias ? bias[k] : 0.f;
    float acc[8];
    #pragma unroll
    for (int r=0;r<8;r++) acc[r] = b0;
    if (mode==0){
      for (int i=0;i<inner;i++){
        float wv = W[(size_t)i*ldw + k];
        #pragma unroll
        for (int r=0;r<8;r++) acc[r] += xs[r][i]*wv;
      }
    } else {
      const float* wr = W + (size_t)k*ldw + offw;
      for (int i=0;i<inner;i++){
        float wv = wr[i];
        #pragma unroll
        for (int r=0;r<8;r++) acc[r] += xs[r][i]*wv;
      }
    }
    for (int r=0;r<nr;r++) out[(size_t)(r0+r)*K + k] = acc[r];
  }
}

// ---- GRU scan: gi precomputed [B,S,450]; thread k<450 holds Whh row k in VGPRs.
__global__ __launch_bounds__(512,2) void gru_scan_kernel(
    const float* __restrict__ gi, const float* __restrict__ Whh,
    const float* __restrict__ bhh, float* __restrict__ Hs, int S)
{
  const int b = blockIdx.x;
  gi += (size_t)b*S*450;
  Hs += (size_t)b*S*HID;
  __shared__ float h[152];
  __shared__ float gh[456];
  const int tid = threadIdx.x;
  float wreg[150];
  float br = 0.f;
  if (tid < 450){
    const float* wr = Whh + (size_t)tid*150;
    #pragma unroll
    for (int i=0;i<150;i++) wreg[i] = wr[i];
    br = bhh[tid];
  }
  if (tid < 150) h[tid] = 0.f;
  __syncthreads();
  for (int t=0;t<S;t++){
    float g0=0.f,g1=0.f,g2=0.f;
    if (tid < 150){
      const float* g = gi + (size_t)t*450;
      g0 = g[tid]; g1 = g[150+tid]; g2 = g[300+tid];
    }
    if (tid < 450){
      float a0=0.f,a1=0.f,a2=0.f,a3=0.f;
      #pragma unroll
      for (int i=0;i<148;i+=4){
        a0 += h[i]  *wreg[i];
        a1 += h[i+1]*wreg[i+1];
        a2 += h[i+2]*wreg[i+2];
        a3 += h[i+3]*wreg[i+3];
      }
      a0 += h[148]*wreg[148];
      a1 += h[149]*wreg[149];
      gh[tid] = br + (a0+a1) + (a2+a3);
    }
    __syncthreads();
    if (tid < 150){
      float r = sigm(g0 + gh[tid]);
      float z = sigm(g1 + gh[150+tid]);
      float n = tanh_f(g2 + r*gh[300+tid]);
      float hn = (1.f-z)*n + z*h[tid];
      h[tid] = hn;
      Hs[(size_t)t*HID + tid] = hn;
    }
    __syncthreads();
  }
}

__global__ void zero_hr0_kernel(float* __restrict__ Hr){
  int idx = blockIdx.x*blockDim.x + threadIdx.x;
  if (idx < NBATCH*300){
    int b = idx/300, k = idx - 300*b;
    Hr[(size_t)b*T1*300 + k] = 0.f;
  }
}

// ---- match scan: one block per (batch, dir). Registers: m_Whh row (150) +
// Wr column segment (50). LDS: P[30x450] (attention-folded Wih_q).
__global__ __launch_bounds__(512,2) void match_scan_kernel(
    const float* __restrict__ pWp,   // [B,T,150]  Hp@Wp + gate_bias
    const float* __restrict__ whq,   // [B,J,150]  Hq@Wq
    const float* __restrict__ giXf,  // [B,T,450]  Hp@m_Wih_x^T + m_bih
    const float* __restrict__ giXr,
    const float* __restrict__ Pf,    // [B,J,450]  Hq@m_Wih_q^T
    const float* __restrict__ Pr,
    const float* __restrict__ m_Whh, const float* __restrict__ mr_Whh,
    const float* __restrict__ m_bhh, const float* __restrict__ mr_bhh,
    const float* __restrict__ Wr,    // [150,150]
    const float* __restrict__ wvec,  // [150]
    float* __restrict__ Hr)          // [B,401,300]
{
  const int b   = blockIdx.x;
  const int dir = blockIdx.y;
  const float* giX = dir ? giXr : giXf;
  const float* P   = dir ? Pr   : Pf;
  const float* Whh = dir ? mr_Whh : m_Whh;
  const float* bhh = dir ? mr_bhh : m_bhh;

  __shared__ float Pl[13500];      // 54 KB
  __shared__ float wl[152];
  __shared__ float h[152];
  __shared__ float pA[456];        // Wr partials (3 segments x 150)
  __shared__ float sc[32], attw[32];
  __shared__ float gis[456], ghs[456];

  const int tid = threadIdx.x;
  const int lane = tid & 63;
  const int wv = tid >> 6;

  float whr[150];                  // m_Whh row `tid`
  float wrr[50];                   // Wr[seg*50 .. seg*50+49][kw]
  float br = 0.f;
  const int kw = (tid < 450) ? (tid % 150) : 0;
  const int seg = (tid < 450) ? (tid / 150) : 0;
  if (tid < 450){
    const float* wr_ = Whh + (size_t)tid*150;
    #pragma unroll
    for (int i=0;i<150;i++) whr[i] = wr_[i];
    br = bhh[tid];
    #pragma unroll
    for (int ii=0;ii<50;ii++) wrr[ii] = Wr[(size_t)(seg*50+ii)*150 + kw];
  }
  for (int e=tid; e<13500; e+=blockDim.x) Pl[e] = P[(size_t)b*13500 + e];
  if (tid < 150){ wl[tid] = wvec[tid]; h[tid] = 0.f; }
  __syncthreads();

  const float* wq = whq + (size_t)b*JQ*150;
  for (int t=0;t<TLEN;t++){
    const int tt = dir ? (TLEN-1-t) : t;
    const float* pw = pWp + ((size_t)b*TLEN + tt)*150;
    // prefetch current-step globals (overlap with phase A compute)
    float gv = (tid < 450) ? giX[((size_t)b*TLEN + tt)*450 + tid] : 0.f;
    float pw0 = pw[lane];
    float pw1 = pw[lane+64];
    float pw2 = (lane+128 < 150) ? pw[lane+128] : 0.f;

    // A: gh = bhh + h@Whh^T (regs) and Wr partial products
    if (tid < 450){
      float a0=0.f,a1=0.f,a2=0.f,a3=0.f;
      #pragma unroll
      for (int i=0;i<148;i+=4){
        a0 += h[i]  *whr[i];
        a1 += h[i+1]*whr[i+1];
        a2 += h[i+2]*whr[i+2];
        a3 += h[i+3]*whr[i+3];
      }
      a0 += h[148]*whr[148];
      a1 += h[149]*whr[149];
      ghs[tid] = br + (a0+a1) + (a2+a3);
      float b0=0.f,b1=0.f;
      #pragma unroll
      for (int u=0;u<50;u+=2){
        b0 += h[seg*50+u]  *wrr[u];
        b1 += h[seg*50+u+1]*wrr[u+1];
      }
      pA[tid] = b0+b1;
    }
    __syncthreads();

    // B: attention scores s[j] = sum_h w[h]*tanh(whq[j,h] + pWp[h] + hWr[h])
    for (int j=wv; j<JQ; j+=8){
      float acc = 0.f;
      {
        float hw = pA[lane] + pA[150+lane] + pA[300+lane];
        acc += wl[lane]*tanh_f(wq[j*150+lane] + pw0 + hw);
      }
      {
        int hh = lane+64;
        float hw = pA[hh] + pA[150+hh] + pA[300+hh];
        acc += wl[hh]*tanh_f(wq[j*150+hh] + pw1 + hw);
      }
      if (lane+128 < 150){
        int hh = lane+128;
        float hw = pA[hh] + pA[150+hh] + pA[300+hh];
        acc += wl[hh]*tanh_f(wq[j*150+hh] + pw2 + hw);
      }
      #pragma unroll
      for (int off=32; off; off>>=1) acc += __shfl_down(acc, off);
      if (lane==0) sc[j] = acc;
    }
    __syncthreads();

    // C: softmax over J=30 (wave 0)
    if (tid < 64){
      float v = (tid < JQ) ? sc[tid] : -1e30f;
      float m = v;
      #pragma unroll
      for (int off=32; off; off>>=1) m = fmaxf(m, __shfl_down(m, off));
      m = __shfl(m, 0);
      float e = (tid < JQ) ? __expf(v-m) : 0.f;
      float s = e;
      #pragma unroll
      for (int off=32; off; off>>=1) s += __shfl_down(s, off);
      s = __shfl(s, 0);
      if (tid < JQ) attw[tid] = e/s;
    }
    __syncthreads();

    // D: gi = giX + sum_j attw[j]*P[j,:]
    if (tid < 450){
      float a0 = gv, a1 = 0.f;
      #pragma unroll
      for (int j=0;j<JQ;j+=2){
        a0 += attw[j]  *Pl[j*450+tid];
        a1 += attw[j+1]*Pl[(j+1)*450+tid];
      }
      gis[tid] = a0+a1;
    }
    __syncthreads();

    // E: GRU combine, write Hr[b, t+1, dir*150 + k]
    if (tid < 150){
      float r = sigm(gis[tid] + ghs[tid]);
      float z = sigm(gis[150+tid] + ghs[150+tid]);
      float n = tanh_f(gis[300+tid] + r*ghs[300+tid]);
      float hn = (1.f-z)*n + z*h[tid];
      h[tid] = hn;
      Hr[((size_t)b*T1 + (t+1))*300 + dir*150 + tid] = hn;
    }
    __syncthreads();
  }
}

// ---- pointer decoder: L=2 steps; writes output probs (fp32 or bf16).
__global__ __launch_bounds__(512,2) void ptr_scan_kernel(
    const float* __restrict__ enc,   // [B,401,300] Hr@ptr_W1
    const float* __restrict__ Hr,    // [B,401,300]
    const float* __restrict__ W2,    // [300,300]
    const float* __restrict__ pv,    // [300]
    const float* __restrict__ dWih,  // [900,300]
    const float* __restrict__ dWhh,  // [900,300]
    const float* __restrict__ dbih, const float* __restrict__ dbhh,
    void* __restrict__ outv, const int* __restrict__ flag)
{
  const int b = blockIdx.x;
  const int tid = threadIdx.x;
  const int isbf = *flag;
  __shared__ float h[300], hW2[300], sl[T1], al[T1], c[300];
  __shared__ float gis[900], ghs[900];
  __shared__ float vl[300];
  __shared__ float red[8];
  if (tid < 300){ h[tid] = 0.f; vl[tid] = pv[tid]; }
  __syncthreads();
  for (int l=0;l<2;l++){
    if (tid < 300){
      float a0=0.f,a1=0.f;
      for (int i=0;i<300;i+=2){
        a0 += h[i]  *W2[(size_t)i*300+tid];
        a1 += h[i+1]*W2[(size_t)(i+1)*300+tid];
      }
      hW2[tid] = a0+a1;
    }
    __syncthreads();
    {
      const int wv = tid>>6, lane = tid&63;
      for (int t=wv; t<T1; t+=8){
        const float* er = enc + ((size_t)b*T1 + t)*300;
        float acc = 0.f;
        for (int k=lane; k<300; k+=64) acc += vl[k]*tanh_f(er[k] + hW2[k]);
        #pragma unroll
        for (int off=32; off; off>>=1) acc += __shfl_down(acc, off);
        if (lane==0) sl[t] = acc;
      }
    }
    __syncthreads();
    {
      float v = (tid < T1) ? sl[tid] : -1e30f;
      float m = v;
      #pragma unroll
      for (int off=32; off; off>>=1) m = fmaxf(m, __shfl_down(m, off));
      if ((tid&63)==0) red[tid>>6] = m;
      __syncthreads();
      float bm = fmaxf(fmaxf(fmaxf(red[0],red[1]),fmaxf(red[2],red[3])),
                       fmaxf(fmaxf(red[4],red[5]),fmaxf(red[6],red[7])));
      float e = (tid < T1) ? __expf(v-bm) : 0.f;
      float s = e;
      #pragma unroll
      for (int off=32; off; off>>=1) s += __shfl_down(s, off);
      __syncthreads();
      if ((tid&63)==0) red[tid>>6] = s;
      __syncthreads();
      float bs = red[0]+red[1]+red[2]+red[3]+red[4]+red[5]+red[6]+red[7];
      if (tid < T1){
        float a = e/bs;
        al[tid] = a;
        size_t oi = ((size_t)b*2 + l)*T1 + tid;
        if (isbf) ((__hip_bfloat16*)outv)[oi] = __float2bfloat16(a);
        else      ((float*)outv)[oi] = a;
      }
    }
    __syncthreads();
    if (tid < 300){
      float acc = 0.f;
      for (int t=0;t<T1;t++) acc += al[t]*Hr[((size_t)b*T1 + t)*300 + tid];
      c[tid] = acc;
    }
    __syncthreads();
    for (int k=tid; k<900; k+=blockDim.x){
      const float* wi = dWih + (size_t)k*300;
      const float* wh = dWhh + (size_t)k*300;
      float a0 = dbih[k], a1 = dbhh[k];
      for (int i=0;i<300;i++){ a0 += c[i]*wi[i]; a1 += h[i]*wh[i]; }
      gis[k] = a0; ghs[k] = a1;
    }
    __syncthreads();
    if (tid < 300){
      float r = sigm(gis[tid] + ghs[tid]);
      float z = sigm(gis[300+tid] + ghs[300+tid]);
      float n = tanh_f(gis[600+tid] + r*ghs[600+tid]);
      h[tid] = (1.f-z)*n + z*h[tid];
    }
    __syncthreads();
  }
}

} // namespace

extern "C" void kernel_launch(void* const* d_in, const int* in_sizes, int n_in,
                              void* d_out, int out_size, void* d_ws, size_t ws_size,
                              hipStream_t stream)
{
  (void)in_sizes; (void)n_in; (void)out_size; (void)ws_size;
  float* ws = (float*)d_ws;
  int* flag = (int*)d_ws;          // ws[0..3]: dtype flag

  static const int wsz[NW] = {
    67500,67500,450,450,          // ctx_Wih/Whh/bih/bhh
    67500,67500,450,450,          // q_*
    22500,22500,22500,150,150,1,  // Wq,Wp,Wr,w,gate_bias,attn_bias
    135000,67500,450,450,         // m_*
    135000,67500,450,450,         // mr_*
    90000,90000,300,              // ptr_W1,ptr_W2,ptr_v
    270000,270000,900,900         // d_*
  };
  WDesc desc;
  int cum = 0;
  for (int j=0;j<NW;j++){ desc.src[j] = d_in[3+j]; desc.off[j] = cum; cum += wsz[j]; }
  desc.off[NW] = cum;  // 1,468,501

  float* WB = ws + 16;
  const float* P_ctx_Wih = WB + desc.off[0];
  const float* P_ctx_bih = WB + desc.off[2];
  const float* P_ctx_Whh = WB + desc.off[1];
  const float* P_ctx_bhh = WB + desc.off[3];
  const float* P_q_Wih   = WB + desc.off[4];
  const float* P_q_Whh   = WB + desc.off[5];
  const float* P_q_bih   = WB + desc.off[6];
  const float* P_q_bhh   = WB + desc.off[7];
  const float* P_Wq      = WB + desc.off[8];
  const float* P_Wp      = WB + desc.off[9];
  const float* P_Wr      = WB + desc.off[10];
  const float* P_w       = WB + desc.off[11];
  const float* P_gb      = WB + desc.off[12];
  const float* P_m_Wih   = WB + desc.off[14];
  const float* P_m_Whh   = WB + desc.off[15];
  const float* P_m_bih   = WB + desc.off[16];
  const float* P_m_bhh   = WB + desc.off[17];
  const float* P_mr_Wih  = WB + desc.off[18];
  const float* P_mr_Whh  = WB + desc.off[19];
  const float* P_mr_bih  = WB + desc.off[20];
  const float* P_mr_bhh  = WB + desc.off[21];
  const float* P_W1      = WB + desc.off[22];
  const float* P_W2      = WB + desc.off[23];
  const float* P_pv      = WB + desc.off[24];
  const float* P_dWih    = WB + desc.off[25];
  const float* P_dWhh    = WB + desc.off[26];
  const float* P_dbih    = WB + desc.off[27];
  const float* P_dbhh    = WB + desc.off[28];

  size_t p = 16 + 1468512;
  float* ctx_gi = ws + p; p += 5760000;   // [B,T,450]; reused for enc later
  float* q_gi   = ws + p; p += 432000;    // [B,J,450]
  float* HpB    = ws + p; p += 1920000;   // [B,T,150]
  float* HqB    = ws + p; p += 144000;    // [B,J,150]
  float* whqB   = ws + p; p += 144000;    // [B,J,150]
  float* PfB    = ws + p; p += 432000;    // [B,J,450]
  float* PrB    = ws + p; p += 432000;
  float* pWpB   = ws + p; p += 1920000;   // [B,T,150]
  float* giXfB  = ws + p; p += 5760000;   // [B,T,450]
  float* giXrB  = ws + p; p += 5760000;
  float* HrB    = ws + p; p += 3849600;   // [B,401,300]
  float* encB   = ctx_gi;                 // [B,401,300] (ctx_gi dead by then)

  // 1) dtype sniff + weight conversion to packed fp32
  sniff_kernel<<<1,256,0,stream>>>((const unsigned int*)d_in[2], flag);
  convert_weights_kernel<<<512,256,0,stream>>>(desc, WB, flag);

  // 2) embedding + input projections for both encoders
  rowproj_kernel<<<1600,512,0,stream>>>(nullptr,(const int*)d_in[0], d_in[2], flag,
                                        P_ctx_Wih, P_ctx_bih, ctx_gi, 12800,450,150,1,150,0);
  rowproj_kernel<<<120,512,0,stream>>>(nullptr,(const int*)d_in[1], d_in[2], flag,
                                       P_q_Wih, P_q_bih, q_gi, 960,450,150,1,150,0);

  // 3) encoder scans
  gru_scan_kernel<<<32,512,0,stream>>>(ctx_gi, P_ctx_Whh, P_ctx_bhh, HpB, 400);
  gru_scan_kernel<<<32,512,0,stream>>>(q_gi,   P_q_Whh,   P_q_bhh,   HqB, 30);

  // 4) Hq/Hp-dependent precomputations
  rowproj_kernel<<<120,192,0,stream>>>(HqB,nullptr,nullptr,nullptr, P_Wq, nullptr,
                                       whqB, 960,150,150,0,150,0);
  rowproj_kernel<<<120,512,0,stream>>>(HqB,nullptr,nullptr,nullptr, P_m_Wih, nullptr,
                                       PfB, 960,450,150,1,300,150);
  rowproj_kernel<<<120,512,0,stream>>>(HqB,nullptr,nullptr,nullptr, P_mr_Wih, nullptr,
                                       PrB, 960,450,150,1,300,150);
  rowproj_kernel<<<1600,192,0,stream>>>(HpB,nullptr,nullptr,nullptr, P_Wp, P_gb,
                                        pWpB, 12800,150,150,0,150,0);
  rowproj_kernel<<<1600,512,0,stream>>>(HpB,nullptr,nullptr,nullptr, P_m_Wih, P_m_bih,
                                        giXfB, 12800,450,150,1,300,0);
  rowproj_kernel<<<1600,512,0,stream>>>(HpB,nullptr,nullptr,nullptr, P_mr_Wih, P_mr_bih,
                                        giXrB, 12800,450,150,1,300,0);

  // 5) match scans (fwd+bwd concurrent)
  zero_hr0_kernel<<<(NBATCH*300+511)/512,512,0,stream>>>(HrB);
  match_scan_kernel<<<dim3(NBATCH,2),512,0,stream>>>(pWpB, whqB, giXfB, giXrB,
                                                     PfB, PrB, P_m_Whh, P_mr_Whh,
                                                     P_m_bhh, P_mr_bhh, P_Wr, P_w, HrB);

  // 6) pointer decoder
  rowproj_kernel<<<1604,320,0,stream>>>(HrB,nullptr,nullptr,nullptr, P_W1, nullptr,
                                        encB, 12832,300,300,0,300,0);
  ptr_scan_kernel<<<32,512,0,stream>>>(encB, HrB, P_W2, P_pv,
                                       P_dWih, P_dWhh, P_dbih, P_dbhh, d_out, flag);
}